// Round 2
// baseline (29553.827 us; speedup 1.0000x reference)
//
#include <hip/hip_runtime.h>
#include <math.h>

// Persistent cooperative LSTM: 256 WGs x 512 threads, 1 WG/CU.
// WG w owns hidden units [8w, 8w+8). wave u = unit, 16-lane group g = gate.
// Folded weights W' = W_hh + (w1+w2) (x) W_lin live in regs (128/thread).
// Sync: single fused tag+value 64-bit word per unit per step.
//   producer: store ((t+1)<<32 | bits(h))  -> consumers poll until tag==t+1
// One __syncthreads per step; LDS h double-buffered by step parity.

#define HDIM 2048
#define TSTEPS 4096
#define NWG 256
#define NTH 512  // 8 waves

typedef unsigned long long u64;

__device__ __forceinline__ float sigmoidf_(float x) {
    return 1.0f / (1.0f + expf(-x));
}

__global__ __launch_bounds__(NTH, 2)
void weld_lstm_persistent(const float* __restrict__ src,
                          const float* __restrict__ W_ih,
                          const float* __restrict__ W_hh,
                          const float* __restrict__ b_ih,
                          const float* __restrict__ b_hh,
                          const float* __restrict__ W_lin,
                          const float* __restrict__ b_lin,
                          float* __restrict__ out,
                          u64* __restrict__ h_buf)
{
    __shared__ float h_lds[2][HDIM];   // double-buffered h (8 KiB each)
    __shared__ float s_lds[TSTEPS];    // 16 KiB: src[0,t,0]
    __shared__ float wlin_lds[HDIM];   // 8 KiB: W_lin row

    const int wg   = blockIdx.x;       // 0..255
    const int tid  = threadIdx.x;      // 0..511
    const int wave = tid >> 6;         // unit sub-index u, 0..7
    const int lane = tid & 63;
    const int g    = lane >> 4;        // gate 0..3 (i,f,g,o)
    const int sub  = lane & 15;        // column-slice within row
    const int unit = wg * 8 + wave;    // hidden unit owned by this wave
    const int row  = g * HDIM + unit;  // W_hh row for (unit, gate)

    // ---- one-time init ----
    for (int i = tid; i < TSTEPS; i += NTH) s_lds[i] = src[3 * i];
    for (int i = tid; i < HDIM;   i += NTH) wlin_lds[i] = W_lin[i];
    for (int i = tid; i < HDIM;   i += NTH) h_lds[0][i] = 0.0f;  // h_{-1}=0

    const float s01  = src[1];
    const float s02  = src[2];
    const float blin = b_lin[0];

    const float w0    = W_ih[row * 3 + 0];
    const float w1    = W_ih[row * 3 + 1];
    const float w2    = W_ih[row * 3 + 2];
    const float w12   = w1 + w2;
    const float braw  = b_ih[row] + b_hh[row];
    const float bfold = braw + w12 * blin;

    // Register-resident folded weights: W'[row,c] = W_hh[row,c] + w12*W_lin[c]
    // This lane's columns: c = k*64 + sub*4 + {0..3}, k = 0..31.
    float wreg[128];
    {
        const float* wrow = W_hh + (size_t)row * HDIM;
        #pragma unroll
        for (int k = 0; k < 32; ++k) {
            const int c = k * 64 + sub * 4;
            float4 wv = *reinterpret_cast<const float4*>(wrow + c);
            float4 lv = *reinterpret_cast<const float4*>(W_lin + c);
            wreg[k * 4 + 0] = wv.x + w12 * lv.x;
            wreg[k * 4 + 1] = wv.y + w12 * lv.y;
            wreg[k * 4 + 2] = wv.z + w12 * lv.z;
            wreg[k * 4 + 3] = wv.w + w12 * lv.w;
        }
    }

    __syncthreads();

    float c_state = 0.0f;  // replicated across the wave's 64 lanes

    const int u0  = tid * 4;            // units this thread polls
    const bool self = ((u0 >> 3) == wg); // units produced by this very WG

    for (int t = 0; t < TSTEPS; ++t) {
        const int rb = t & 1;      // LDS buffer holding h_{t-1}
        const int wb = rb ^ 1;     // LDS buffer receiving h_t

        // input contribution (independent of h — off critical path)
        float xterm;
        if (t == 0) {
            xterm = braw + w0 * s_lds[0] + w1 * s01 + w2 * s02;
        } else {
            xterm = bfold + w0 * s_lds[t];
        }

        // matvec partial over this lane's 128 columns
        float a0 = 0.0f, a1 = 0.0f, a2 = 0.0f, a3 = 0.0f;
        #pragma unroll
        for (int k = 0; k < 32; ++k) {
            const int c = k * 64 + sub * 4;
            float4 h4 = *reinterpret_cast<const float4*>(&h_lds[rb][c]);
            a0 += wreg[k * 4 + 0] * h4.x;
            a1 += wreg[k * 4 + 1] * h4.y;
            a2 += wreg[k * 4 + 2] * h4.z;
            a3 += wreg[k * 4 + 3] * h4.w;
        }
        float sum = (a0 + a1) + (a2 + a3);
        sum += __shfl_xor(sum, 1);
        sum += __shfl_xor(sum, 2);
        sum += __shfl_xor(sum, 4);
        sum += __shfl_xor(sum, 8);
        const float gate = sum + xterm;

        const float gi = __shfl(gate, 0);
        const float gf = __shfl(gate, 16);
        const float gg = __shfl(gate, 32);
        const float go = __shfl(gate, 48);
        c_state = sigmoidf_(gf) * c_state + sigmoidf_(gi) * tanhf(gg);
        const float h_new = sigmoidf_(go) * tanhf(c_state);

        // publish: fused (tag | value), plus LDS shortcut for own units
        u64* hb = h_buf + (size_t)rb * HDIM;   // global slot parity = t&1
        if (lane == 0) {
            const u64 p = ((u64)(unsigned)(t + 1) << 32) |
                          (u64)__float_as_uint(h_new);
            __hip_atomic_store(&hb[unit], p,
                               __ATOMIC_RELAXED, __HIP_MEMORY_SCOPE_AGENT);
            h_lds[wb][unit] = h_new;
        }

        // poll 4 units (skip the 8 this WG produced — LDS shortcut above)
        if (!self) {
            const unsigned want = (unsigned)(t + 1);
            u64 v0, v1, v2, v3;
            for (;;) {
                v0 = __hip_atomic_load(&hb[u0 + 0], __ATOMIC_RELAXED, __HIP_MEMORY_SCOPE_AGENT);
                v1 = __hip_atomic_load(&hb[u0 + 1], __ATOMIC_RELAXED, __HIP_MEMORY_SCOPE_AGENT);
                v2 = __hip_atomic_load(&hb[u0 + 2], __ATOMIC_RELAXED, __HIP_MEMORY_SCOPE_AGENT);
                v3 = __hip_atomic_load(&hb[u0 + 3], __ATOMIC_RELAXED, __HIP_MEMORY_SCOPE_AGENT);
                if ((unsigned)(v0 >> 32) == want && (unsigned)(v1 >> 32) == want &&
                    (unsigned)(v2 >> 32) == want && (unsigned)(v3 >> 32) == want)
                    break;
            }
            float4 hv;
            hv.x = __uint_as_float((unsigned)v0);
            hv.y = __uint_as_float((unsigned)v1);
            hv.z = __uint_as_float((unsigned)v2);
            hv.w = __uint_as_float((unsigned)v3);
            *reinterpret_cast<float4*>(&h_lds[wb][u0]) = hv;
        }

        __syncthreads();  // h_lds[wb] complete -> becomes h_{t} for step t+1

        // y_t = W_lin . h_t + b_lin, by owner WG (t % 256), wave 7
        if (wg == (t & (NWG - 1)) && wave == 7) {
            float ysum = 0.0f;
            #pragma unroll
            for (int k = 0; k < 32; ++k) {
                ysum += wlin_lds[k * 64 + lane] * h_lds[wb][k * 64 + lane];
            }
            ysum += __shfl_xor(ysum, 1);
            ysum += __shfl_xor(ysum, 2);
            ysum += __shfl_xor(ysum, 4);
            ysum += __shfl_xor(ysum, 8);
            ysum += __shfl_xor(ysum, 16);
            ysum += __shfl_xor(ysum, 32);
            if (lane == 0) out[t] = ysum + blin;
        }
    }
}

extern "C" void kernel_launch(void* const* d_in, const int* in_sizes, int n_in,
                              void* d_out, int out_size, void* d_ws, size_t ws_size,
                              hipStream_t stream) {
    const float* src   = (const float*)d_in[0];
    const float* W_ih  = (const float*)d_in[1];
    const float* W_hh  = (const float*)d_in[2];
    const float* b_ih  = (const float*)d_in[3];
    const float* b_hh  = (const float*)d_in[4];
    const float* W_lin = (const float*)d_in[5];
    const float* b_lin = (const float*)d_in[6];
    float* out = (float*)d_out;

    // ws: [0, 32 KiB) = h_buf: 2 (parity) x 2048 units x 8 B packed tag|value.
    // Cleared every launch so stale tags from a previous replay can't match.
    u64* h_buf = (u64*)d_ws;
    hipMemsetAsync(d_ws, 0, 2 * HDIM * sizeof(u64), stream);

    void* args[] = { &src, &W_ih, &W_hh, &b_ih, &b_hh, &W_lin, &b_lin,
                     &out, &h_buf };
    hipLaunchCooperativeKernel((const void*)weld_lstm_persistent,
                               dim3(NWG), dim3(NTH), args, 0, stream);
}